// Round 2
// baseline (536.442 us; speedup 1.0000x reference)
//
#include <hip/hip_runtime.h>

typedef _Float16 f16;
typedef __attribute__((ext_vector_type(8))) _Float16 f16x8;
typedef __attribute__((ext_vector_type(4))) _Float16 f16x4;
typedef __attribute__((ext_vector_type(4))) float f32x4;

// Problem constants
constexpr int BB = 8;
constexpr int NN = 2048;
constexpr int CC = 1024;
constexpr int MTOT = BB * NN;     // 16384
constexpr int KKEEP = 1638;

// ---------------------------------------------------------------------------
// async 16B global -> LDS (wave-uniform LDS base + lane*16 is implicit in HW)
// ---------------------------------------------------------------------------
__device__ __forceinline__ void gl_lds16(const void* g, void* l) {
  __builtin_amdgcn_global_load_lds((__attribute__((address_space(1))) void*)g,
                                   (__attribute__((address_space(3))) void*)l,
                                   16, 0, 0);
}

// ---------------------------------------------------------------------------
// fp32 -> fp16 conversion (vectorized float4 -> f16x4)
// ---------------------------------------------------------------------------
__global__ __launch_bounds__(256) void cvt_f32_f16(const float* __restrict__ s,
                                                   f16* __restrict__ d, int n4) {
  int i = blockIdx.x * 256 + threadIdx.x;
  if (i < n4) {
    float4 f = ((const float4*)s)[i];
    f16x4 o = {(f16)f.x, (f16)f.y, (f16)f.z, (f16)f.w};
    ((f16x4*)d)[i] = o;
  }
}

// ---------------------------------------------------------------------------
// GEMM-BT core:  C[m][n] = sum_k A[m][k] * B[n][k]   (both operands k-contig)
// 128x128 tile, BK=32, 256 threads = 4 waves (2x2), each wave 64x64 = 4x4
// fragments of mfma_f32_16x16x32_f16.
// MODE 0: fp32 out, * scale               (S and PV GEMMs)
// MODE 1: f16 out, + bias[n]              (Q, K projections)
// MODE 2: f16 out transposed Ct[n][m], + bias[n]  (V projection -> Vt)
// ---------------------------------------------------------------------------
template <int MODE>
__global__ __launch_bounds__(256, 2) void gemm_bt(
    const f16* __restrict__ A, const f16* __restrict__ B,
    const float* __restrict__ bias, void* __restrict__ Cout,
    int K, int lda, int ldb, int ldc, float scale, int ldct,
    long strideA, long strideB, long strideC) {
  const f16* Ab = A + (size_t)blockIdx.z * strideA;
  const f16* Bbp = B + (size_t)blockIdx.z * strideB;

  const int bm = blockIdx.x * 128;
  const int bn = blockIdx.y * 128;
  const int tid = threadIdx.x;
  const int wave = tid >> 6;
  const int lane = tid & 63;
  const int wy = wave >> 1, wx = wave & 1;

  __shared__ f16 As[128 * 32];
  __shared__ f16 Bs[128 * 32];

  f32x4 acc[4][4];
#pragma unroll
  for (int i = 0; i < 4; i++)
#pragma unroll
    for (int j = 0; j < 4; j++) acc[i][j] = (f32x4){0.f, 0.f, 0.f, 0.f};

  // staging: wave w covers tile rows [w*32, w*32+32), 2 insts x 16 rows each,
  // lane l -> row chunk + (l>>2), col (l&3)*8  => LDS offset = lane*8 elems.
  const int sr = wave * 32 + (lane >> 2);
  const int sc = (lane & 3) * 8;
  const f16* gA0 = Ab + (size_t)(bm + sr) * lda + sc;
  const f16* gA1 = gA0 + (size_t)16 * lda;
  const f16* gB0 = Bbp + (size_t)(bn + sr) * ldb + sc;
  const f16* gB1 = gB0 + (size_t)16 * ldb;
  f16* lA0 = As + (wave * 32) * 32;
  f16* lA1 = As + (wave * 32 + 16) * 32;
  f16* lB0 = Bs + (wave * 32) * 32;
  f16* lB1 = Bs + (wave * 32 + 16) * 32;

  // fragment read coords: A[m=lane&15][k=(lane>>4)*8+j]
  const int frm = wy * 64 + (lane & 15);
  const int frn = wx * 64 + (lane & 15);
  const int kq = (lane >> 4) * 8;

  for (int k0 = 0; k0 < K; k0 += 32) {
    gl_lds16(gA0 + k0, lA0);
    gl_lds16(gA1 + k0, lA1);
    gl_lds16(gB0 + k0, lB0);
    gl_lds16(gB1 + k0, lB1);
    __syncthreads();  // drains vmcnt before barrier
    f16x8 av[4], bv[4];
#pragma unroll
    for (int i = 0; i < 4; i++)
      av[i] = *(const f16x8*)(As + (frm + 16 * i) * 32 + kq);
#pragma unroll
    for (int i = 0; i < 4; i++)
      bv[i] = *(const f16x8*)(Bs + (frn + 16 * i) * 32 + kq);
#pragma unroll
    for (int i = 0; i < 4; i++)
#pragma unroll
      for (int j = 0; j < 4; j++)
        acc[i][j] =
            __builtin_amdgcn_mfma_f32_16x16x32_f16(av[i], bv[j], acc[i][j], 0, 0, 0);
    __syncthreads();  // protect LDS from next-iter overwrite
  }

  // epilogue: C/D layout col=lane&15, row=(lane>>4)*4 + r
  const int q = lane >> 4;
  const int ci = lane & 15;
#pragma unroll
  for (int i = 0; i < 4; i++) {
#pragma unroll
    for (int j = 0; j < 4; j++) {
      const int row0 = bm + wy * 64 + i * 16 + q * 4;
      const int col = bn + wx * 64 + j * 16 + ci;
      if (MODE == 0) {
        float* C = (float*)Cout + (size_t)blockIdx.z * strideC;
#pragma unroll
        for (int r = 0; r < 4; r++)
          C[(size_t)(row0 + r) * ldc + col] = acc[i][j][r] * scale;
      } else if (MODE == 1) {
        f16* C = (f16*)Cout + (size_t)blockIdx.z * strideC;
        const float bb = bias[col];
#pragma unroll
        for (int r = 0; r < 4; r++)
          C[(size_t)(row0 + r) * ldc + col] = (f16)(acc[i][j][r] + bb);
      } else {
        f16* C = (f16*)Cout;
        const float bb = bias[col];
        f16x4 o;
#pragma unroll
        for (int r = 0; r < 4; r++) o[r] = (f16)(acc[i][j][r] + bb);
        *(f16x4*)(C + (size_t)col * ldct + row0) = o;  // 4 consecutive rows
      }
    }
  }
}

// ---------------------------------------------------------------------------
// Per-row exact top-k(1638) + softmax. One block (256 thr) per row of 2048.
// Thread t owns contiguous elements [8t, 8t+8). Exact radix-select on
// order-transformed fp32 bits; exact tie-break by index (matches lax.top_k).
// Writes P (f16) in place over the fp32 S row (row pitch stays 8192 B).
// ---------------------------------------------------------------------------
__global__ __launch_bounds__(256) void topk_softmax_kernel(float* __restrict__ S) {
  const size_t row = blockIdx.x;
  float* srow = S + row * 2048;
  f16* prow = (f16*)srow;
  const int t = threadIdx.x;

  float v[8];
  float4 f0 = ((const float4*)srow)[2 * t];
  float4 f1 = ((const float4*)srow)[2 * t + 1];
  v[0] = f0.x; v[1] = f0.y; v[2] = f0.z; v[3] = f0.w;
  v[4] = f1.x; v[5] = f1.y; v[6] = f1.z; v[7] = f1.w;

  unsigned u[8];
#pragma unroll
  for (int j = 0; j < 8; j++) {
    unsigned b = __float_as_uint(v[j]);
    u[j] = (b & 0x80000000u) ? ~b : (b | 0x80000000u);  // monotonic order map
  }

  __shared__ int hist[256];
  __shared__ int sA[256], sB[256];
  __shared__ unsigned sh_thr;
  __shared__ int sh_want;
  __shared__ float sh_f[256];

  unsigned prefix = 0;
  int want = KKEEP;
  for (int shift = 24; shift >= 0; shift -= 8) {
    hist[t] = 0;
    __syncthreads();
#pragma unroll
    for (int j = 0; j < 8; j++) {
      bool cand = (shift == 24) || ((u[j] >> (shift + 8)) == (prefix >> (shift + 8)));
      if (cand) atomicAdd(&hist[(u[j] >> shift) & 255], 1);
    }
    __syncthreads();
    // suffix sums cum[b] = sum_{i>=b} hist[i]
    {
      int* src = sA;
      int* dst = sB;
      src[t] = hist[t];
      __syncthreads();
      for (int off = 1; off < 256; off <<= 1) {
        int x = src[t] + ((t + off < 256) ? src[t + off] : 0);
        dst[t] = x;
        __syncthreads();
        int* tmp = src; src = dst; dst = tmp;
      }
      int cum = src[t];
      int above = (t < 255) ? src[t + 1] : 0;
      if (cum >= want && above < want) {
        sh_thr = prefix | ((unsigned)t << shift);
        sh_want = want - above;
      }
    }
    __syncthreads();
    prefix = sh_thr;
    want = sh_want;
    __syncthreads();
  }

  // rank among exact-threshold ties, in index order
  int eqf[8];
  int ceq = 0;
#pragma unroll
  for (int j = 0; j < 8; j++) {
    eqf[j] = (u[j] == prefix) ? 1 : 0;
    ceq += eqf[j];
  }
  int excl;
  {
    int* src = sA;
    int* dst = sB;
    src[t] = ceq;
    __syncthreads();
    for (int off = 1; off < 256; off <<= 1) {
      int x = src[t] + ((t >= off) ? src[t - off] : 0);
      dst[t] = x;
      __syncthreads();
      int* tmp = src; src = dst; dst = tmp;
    }
    excl = src[t] - ceq;
    __syncthreads();
  }

  // block max (global max is always kept)
  float mx = v[0];
#pragma unroll
  for (int j = 1; j < 8; j++) mx = fmaxf(mx, v[j]);
  sh_f[t] = mx;
  __syncthreads();
  for (int s = 128; s > 0; s >>= 1) {
    if (t < s) sh_f[t] = fmaxf(sh_f[t], sh_f[t + s]);
    __syncthreads();
  }
  mx = sh_f[0];
  __syncthreads();

  float e[8];
  float lsum = 0.f;
  int r = excl;
#pragma unroll
  for (int j = 0; j < 8; j++) {
    bool kept;
    if (u[j] > prefix) {
      kept = true;
    } else if (eqf[j]) {
      kept = (r < want);
      r++;
    } else {
      kept = false;
    }
    e[j] = kept ? expf(v[j] - mx) : 0.f;
    lsum += e[j];
  }
  sh_f[t] = lsum;
  __syncthreads();
  for (int s = 128; s > 0; s >>= 1) {
    if (t < s) sh_f[t] += sh_f[t + s];
    __syncthreads();
  }
  const float inv = 1.0f / sh_f[0];

  f16x8 o;
#pragma unroll
  for (int j = 0; j < 8; j++) o[j] = (f16)(e[j] * inv);
  *(f16x8*)(prow + t * 8) = o;  // 16B store, first 4KB of the 8KB row
}

// ---------------------------------------------------------------------------
// launch
//
// Workspace layout (peak 234,881,024 B = 224 MiB; R1 crash was a 262 MiB
// layout likely overrunning a 256 MiB d_ws):
//   [qb 32M][kb 32M][vtb 32M][S fp32 128M]
// with xb (32M) and the three f16 weights (6M) ALIASED into the front of S's
// span — they are dead once the projections finish, and S is written only
// after that (same-stream ordering).
// ---------------------------------------------------------------------------
extern "C" void kernel_launch(void* const* d_in, const int* in_sizes, int n_in,
                              void* d_out, int out_size, void* d_ws, size_t ws_size,
                              hipStream_t stream) {
  (void)in_sizes; (void)n_in; (void)out_size; (void)ws_size;
  const float* x = (const float*)d_in[0];
  const float* Wq = (const float*)d_in[1];
  const float* bq = (const float*)d_in[2];
  const float* Wk = (const float*)d_in[3];
  const float* bk = (const float*)d_in[4];
  const float* Wv = (const float*)d_in[5];
  const float* bv = (const float*)d_in[6];
  float* out = (float*)d_out;

  char* ws = (char*)d_ws;
  f16* qb = (f16*)(ws + 0);            // [16384][1024]  33,554,432 B
  f16* kb = (f16*)(ws + 33554432);     // [16384][1024]
  f16* vtb = (f16*)(ws + 67108864);    // [1024][16384] (V^T)
  float* S = (float*)(ws + 100663296); // [8][2048][2048] fp32 (134,217,728 B)
  // --- aliased into S's span; dead before S is first written ---
  f16* xb = (f16*)(ws + 100663296);    // [16384][1024]  33,554,432 B
  f16* wqb = (f16*)(ws + 134217728);   // [1024][1024]
  f16* wkb = (f16*)(ws + 136314880);
  f16* wvb = (f16*)(ws + 138412032);   // ends 140,509,184 < 234,881,024

  // 1) conversions to fp16
  cvt_f32_f16<<<(MTOT * CC / 4 + 255) / 256, 256, 0, stream>>>(x, xb, MTOT * CC / 4);
  cvt_f32_f16<<<(CC * CC / 4 + 255) / 256, 256, 0, stream>>>(Wq, wqb, CC * CC / 4);
  cvt_f32_f16<<<(CC * CC / 4 + 255) / 256, 256, 0, stream>>>(Wk, wkb, CC * CC / 4);
  cvt_f32_f16<<<(CC * CC / 4 + 255) / 256, 256, 0, stream>>>(Wv, wvb, CC * CC / 4);

  // 2) projections: Q, K (row-major f16) and V stored transposed Vt[1024][16384]
  gemm_bt<1><<<dim3(MTOT / 128, CC / 128, 1), 256, 0, stream>>>(
      xb, wqb, bq, qb, CC, CC, CC, CC, 1.f, 0, 0, 0, 0);
  gemm_bt<1><<<dim3(MTOT / 128, CC / 128, 1), 256, 0, stream>>>(
      xb, wkb, bk, kb, CC, CC, CC, CC, 1.f, 0, 0, 0, 0);
  gemm_bt<2><<<dim3(MTOT / 128, CC / 128, 1), 256, 0, stream>>>(
      xb, wvb, bv, vtb, CC, CC, CC, 0, 1.f, MTOT, 0, 0, 0);

  // 3) scores S[b] = Q[b] K[b]^T / 32  (fp32 out; overwrites dead xb/weights)
  gemm_bt<0><<<dim3(NN / 128, NN / 128, BB), 256, 0, stream>>>(
      qb, kb, nullptr, S, CC, CC, CC, NN, 1.f / 32.f, 0,
      (long)NN * CC, (long)NN * CC, (long)NN * NN);

  // 4) exact top-k + softmax -> P (f16, in place over S; row pitch 4096 f16)
  topk_softmax_kernel<<<MTOT, 256, 0, stream>>>(S);

  // 5) O[b] = P[b] Vt[b]^T  (fp32 out to d_out)
  gemm_bt<0><<<dim3(NN / 128, CC / 128, BB), 256, 0, stream>>>(
      (const f16*)S, vtb, nullptr, out, NN, 2 * NN, MTOT, CC, 1.f, 0,
      (long)NN * 2 * NN, (long)NN, (long)NN * CC);
}

// Round 3
// 534.936 us; speedup vs baseline: 1.0028x; 1.0028x over previous
//
#include <hip/hip_runtime.h>

typedef _Float16 f16;
typedef __attribute__((ext_vector_type(8))) _Float16 f16x8;
typedef __attribute__((ext_vector_type(4))) _Float16 f16x4;
typedef __attribute__((ext_vector_type(4))) float f32x4;

// Problem constants
constexpr int BB = 8;
constexpr int NN = 2048;
constexpr int CC = 1024;
constexpr int MTOT = BB * NN;     // 16384
constexpr int KKEEP = 1638;

// ---------------------------------------------------------------------------
// async 16B global -> LDS
// ---------------------------------------------------------------------------
__device__ __forceinline__ void gl_lds16(const void* g, void* l) {
  __builtin_amdgcn_global_load_lds((__attribute__((address_space(1))) void*)g,
                                   (__attribute__((address_space(3))) void*)l,
                                   16, 0, 0);
}

// ---------------------------------------------------------------------------
// fp32 -> fp16 conversion (vectorized float4 -> f16x4)
// ---------------------------------------------------------------------------
__global__ __launch_bounds__(256) void cvt_f32_f16(const float* __restrict__ s,
                                                   f16* __restrict__ d, int n4) {
  int i = blockIdx.x * 256 + threadIdx.x;
  if (i < n4) {
    float4 f = ((const float4*)s)[i];
    f16x4 o = {(f16)f.x, (f16)f.y, (f16)f.z, (f16)f.w};
    ((f16x4*)d)[i] = o;
  }
}

// ---------------------------------------------------------------------------
// GEMM-BT core:  C[m][n] = sum_k A[m][k] * B[n][k]   (both operands k-contig)
// 128x128 tile, BK=32, 256 threads = 4 waves (2x2), each wave 64x64 = 4x4
// fragments of mfma_f32_16x16x32_f16.
// MODE 0: fp32 out, * scale               (S and PV GEMMs)
// MODE 1: f16 out, + bias[n]              (Q, K projections)
// MODE 2: f16 out transposed Ct[n][m], + bias[n]  (V projection -> Vt)
// ---------------------------------------------------------------------------
template <int MODE>
__global__ __launch_bounds__(256, 2) void gemm_bt(
    const f16* __restrict__ A, const f16* __restrict__ B,
    const float* __restrict__ bias, void* __restrict__ Cout,
    int K, int lda, int ldb, int ldc, float scale, int ldct,
    long strideA, long strideB, long strideC) {
  const f16* Ab = A + (size_t)blockIdx.z * strideA;
  const f16* Bbp = B + (size_t)blockIdx.z * strideB;

  const int bm = blockIdx.x * 128;
  const int bn = blockIdx.y * 128;
  const int tid = threadIdx.x;
  const int wave = tid >> 6;
  const int lane = tid & 63;
  const int wy = wave >> 1, wx = wave & 1;

  __shared__ f16 As[128 * 32];
  __shared__ f16 Bs[128 * 32];

  f32x4 acc[4][4];
#pragma unroll
  for (int i = 0; i < 4; i++)
#pragma unroll
    for (int j = 0; j < 4; j++) acc[i][j] = (f32x4){0.f, 0.f, 0.f, 0.f};

  const int sr = wave * 32 + (lane >> 2);
  const int sc = (lane & 3) * 8;
  const f16* gA0 = Ab + (size_t)(bm + sr) * lda + sc;
  const f16* gA1 = gA0 + (size_t)16 * lda;
  const f16* gB0 = Bbp + (size_t)(bn + sr) * ldb + sc;
  const f16* gB1 = gB0 + (size_t)16 * ldb;
  f16* lA0 = As + (wave * 32) * 32;
  f16* lA1 = As + (wave * 32 + 16) * 32;
  f16* lB0 = Bs + (wave * 32) * 32;
  f16* lB1 = Bs + (wave * 32 + 16) * 32;

  const int frm = wy * 64 + (lane & 15);
  const int frn = wx * 64 + (lane & 15);
  const int kq = (lane >> 4) * 8;

  for (int k0 = 0; k0 < K; k0 += 32) {
    gl_lds16(gA0 + k0, lA0);
    gl_lds16(gA1 + k0, lA1);
    gl_lds16(gB0 + k0, lB0);
    gl_lds16(gB1 + k0, lB1);
    __syncthreads();
    f16x8 av[4], bv[4];
#pragma unroll
    for (int i = 0; i < 4; i++)
      av[i] = *(const f16x8*)(As + (frm + 16 * i) * 32 + kq);
#pragma unroll
    for (int i = 0; i < 4; i++)
      bv[i] = *(const f16x8*)(Bs + (frn + 16 * i) * 32 + kq);
#pragma unroll
    for (int i = 0; i < 4; i++)
#pragma unroll
      for (int j = 0; j < 4; j++)
        acc[i][j] =
            __builtin_amdgcn_mfma_f32_16x16x32_f16(av[i], bv[j], acc[i][j], 0, 0, 0);
    __syncthreads();
  }

  const int q = lane >> 4;
  const int ci = lane & 15;
#pragma unroll
  for (int i = 0; i < 4; i++) {
#pragma unroll
    for (int j = 0; j < 4; j++) {
      const int row0 = bm + wy * 64 + i * 16 + q * 4;
      const int col = bn + wx * 64 + j * 16 + ci;
      if (MODE == 0) {
        float* C = (float*)Cout + (size_t)blockIdx.z * strideC;
#pragma unroll
        for (int r = 0; r < 4; r++)
          C[(size_t)(row0 + r) * ldc + col] = acc[i][j][r] * scale;
      } else if (MODE == 1) {
        f16* C = (f16*)Cout + (size_t)blockIdx.z * strideC;
        const float bb = bias[col];
#pragma unroll
        for (int r = 0; r < 4; r++)
          C[(size_t)(row0 + r) * ldc + col] = (f16)(acc[i][j][r] + bb);
      } else {
        f16* C = (f16*)Cout;
        const float bb = bias[col];
        f16x4 o;
#pragma unroll
        for (int r = 0; r < 4; r++) o[r] = (f16)(acc[i][j][r] + bb);
        *(f16x4*)(C + (size_t)col * ldct + row0) = o;
      }
    }
  }
}

// ---------------------------------------------------------------------------
// Per-row exact top-k(1638) + softmax. One block (256 thr = 4 waves) per row.
// Thread t owns contiguous elements [8t, 8t+8). Exact 4x8-bit radix-select on
// order-transformed fp32 bits; exact tie-break by index (matches lax.top_k).
// R3 rewrite: wave-shuffle scans/reductions (4 barriers/pass vs ~20) and a
// per-wave privatized, bank-interleaved histogram hist[bin*4+wave] (cuts
// same-address LDS atomic serialization ~4x). Selection is bit-identical.
// Writes P (f16) in place over the fp32 S row (row pitch 4096 f16).
// ---------------------------------------------------------------------------
__global__ __launch_bounds__(256) void topk_softmax_kernel(float* __restrict__ S) {
  const size_t row = blockIdx.x;
  float* srow = S + row * 2048;
  f16* prow = (f16*)srow;
  const int t = threadIdx.x;
  const int lane = t & 63;
  const int wave = t >> 6;

  float v[8];
  float4 f0 = ((const float4*)srow)[2 * t];
  float4 f1 = ((const float4*)srow)[2 * t + 1];
  v[0] = f0.x; v[1] = f0.y; v[2] = f0.z; v[3] = f0.w;
  v[4] = f1.x; v[5] = f1.y; v[6] = f1.z; v[7] = f1.w;

  unsigned u[8];
#pragma unroll
  for (int j = 0; j < 8; j++) {
    unsigned b = __float_as_uint(v[j]);
    u[j] = (b & 0x80000000u) ? ~b : (b | 0x80000000u);  // monotonic order map
  }

  __shared__ int hist4[256 * 4];   // [bin][wave] interleaved
  __shared__ int wagg[4];
  __shared__ float wf[4];
  __shared__ unsigned sh_thr;
  __shared__ int sh_want;

  unsigned prefix = 0;
  int want = KKEEP;
  for (int shift = 24; shift >= 0; shift -= 8) {
    ((int4*)hist4)[t] = (int4){0, 0, 0, 0};  // zero my bin's 4 wave slots
    __syncthreads();
#pragma unroll
    for (int j = 0; j < 8; j++) {
      bool cand = (shift == 24) || ((u[j] >> (shift + 8)) == (prefix >> (shift + 8)));
      if (cand) atomicAdd(&hist4[(((u[j] >> shift) & 255) << 2) + wave], 1);
    }
    __syncthreads();
    // h = total count for bin t; suffix-scan (descending bins) via shuffles.
    int4 hh = ((const int4*)hist4)[t];
    int h = hh.x + hh.y + hh.z + hh.w;
    // Within-wave suffix sum over lanes (bin = wave*64 + lane):
    int sfx = h;
#pragma unroll
    for (int off = 1; off < 64; off <<= 1) {
      int o = __shfl_down(sfx, off, 64);
      sfx += (lane + off < 64) ? o : 0;
    }
    if (lane == 0) wagg[wave] = sfx;  // wave total
    __syncthreads();
    int hi = 0;
#pragma unroll
    for (int w = 0; w < 4; w++) hi += (w > wave) ? wagg[w] : 0;
    const int cum = sfx + hi;       // sum of hist over bins >= t
    const int above = cum - h;      // sum over bins > t
    if (cum >= want && above < want) {
      sh_thr = prefix | ((unsigned)t << shift);
      sh_want = want - above;
    }
    __syncthreads();
    prefix = sh_thr;
    want = sh_want;
  }

  // rank among exact-threshold ties, in index order (forward exclusive scan)
  int eqf[8];
  int ceq = 0;
#pragma unroll
  for (int j = 0; j < 8; j++) {
    eqf[j] = (u[j] == prefix) ? 1 : 0;
    ceq += eqf[j];
  }
  int inc = ceq;
#pragma unroll
  for (int off = 1; off < 64; off <<= 1) {
    int o = __shfl_up(inc, off, 64);
    inc += (lane >= off) ? o : 0;
  }
  if (lane == 63) wagg[wave] = inc;
  __syncthreads();
  int pre = 0;
#pragma unroll
  for (int w = 0; w < 4; w++) pre += (w < wave) ? wagg[w] : 0;
  const int excl = pre + inc - ceq;

  // block max via butterfly + cross-wave combine
  float mx = v[0];
#pragma unroll
  for (int j = 1; j < 8; j++) mx = fmaxf(mx, v[j]);
#pragma unroll
  for (int off = 32; off > 0; off >>= 1) mx = fmaxf(mx, __shfl_xor(mx, off, 64));
  if (lane == 0) wf[wave] = mx;
  __syncthreads();
  mx = fmaxf(fmaxf(wf[0], wf[1]), fmaxf(wf[2], wf[3]));
  __syncthreads();  // wf reused below

  float e[8];
  float lsum = 0.f;
  int r = excl;
#pragma unroll
  for (int j = 0; j < 8; j++) {
    bool kept;
    if (u[j] > prefix) {
      kept = true;
    } else if (eqf[j]) {
      kept = (r < want);
      r++;
    } else {
      kept = false;
    }
    e[j] = kept ? __expf(v[j] - mx) : 0.f;
    lsum += e[j];
  }
#pragma unroll
  for (int off = 32; off > 0; off >>= 1) lsum += __shfl_xor(lsum, off, 64);
  if (lane == 0) wf[wave] = lsum;
  __syncthreads();
  const float inv = 1.0f / (wf[0] + wf[1] + wf[2] + wf[3]);

  f16x8 o;
#pragma unroll
  for (int j = 0; j < 8; j++) o[j] = (f16)(e[j] * inv);
  *(f16x8*)(prow + t * 8) = o;  // 16B store, first 4KB of the 8KB row
}

// ---------------------------------------------------------------------------
// launch
//
// Workspace layout (peak 224 MiB):
//   [qb 32M][kb 32M][vtb 32M][S fp32 128M]
// with xb (32M) and the three f16 weights (6M) ALIASED into the front of S's
// span — dead once the projections finish; S written only after that.
// ---------------------------------------------------------------------------
extern "C" void kernel_launch(void* const* d_in, const int* in_sizes, int n_in,
                              void* d_out, int out_size, void* d_ws, size_t ws_size,
                              hipStream_t stream) {
  (void)in_sizes; (void)n_in; (void)out_size; (void)ws_size;
  const float* x = (const float*)d_in[0];
  const float* Wq = (const float*)d_in[1];
  const float* bq = (const float*)d_in[2];
  const float* Wk = (const float*)d_in[3];
  const float* bk = (const float*)d_in[4];
  const float* Wv = (const float*)d_in[5];
  const float* bv = (const float*)d_in[6];
  float* out = (float*)d_out;

  char* ws = (char*)d_ws;
  f16* qb = (f16*)(ws + 0);            // [16384][1024]  33,554,432 B
  f16* kb = (f16*)(ws + 33554432);     // [16384][1024]
  f16* vtb = (f16*)(ws + 67108864);    // [1024][16384] (V^T)
  float* S = (float*)(ws + 100663296); // [8][2048][2048] fp32 (134,217,728 B)
  // --- aliased into S's span; dead before S is first written ---
  f16* xb = (f16*)(ws + 100663296);    // [16384][1024]
  f16* wqb = (f16*)(ws + 134217728);
  f16* wkb = (f16*)(ws + 136314880);
  f16* wvb = (f16*)(ws + 138412032);

  // 1) conversions to fp16
  cvt_f32_f16<<<(MTOT * CC / 4 + 255) / 256, 256, 0, stream>>>(x, xb, MTOT * CC / 4);
  cvt_f32_f16<<<(CC * CC / 4 + 255) / 256, 256, 0, stream>>>(Wq, wqb, CC * CC / 4);
  cvt_f32_f16<<<(CC * CC / 4 + 255) / 256, 256, 0, stream>>>(Wk, wkb, CC * CC / 4);
  cvt_f32_f16<<<(CC * CC / 4 + 255) / 256, 256, 0, stream>>>(Wv, wvb, CC * CC / 4);

  // 2) projections: Q, K (row-major f16) and V stored transposed Vt[1024][16384]
  gemm_bt<1><<<dim3(MTOT / 128, CC / 128, 1), 256, 0, stream>>>(
      xb, wqb, bq, qb, CC, CC, CC, CC, 1.f, 0, 0, 0, 0);
  gemm_bt<1><<<dim3(MTOT / 128, CC / 128, 1), 256, 0, stream>>>(
      xb, wkb, bk, kb, CC, CC, CC, CC, 1.f, 0, 0, 0, 0);
  gemm_bt<2><<<dim3(MTOT / 128, CC / 128, 1), 256, 0, stream>>>(
      xb, wvb, bv, vtb, CC, CC, CC, 0, 1.f, MTOT, 0, 0, 0);

  // 3) scores S[b] = Q[b] K[b]^T / 32  (fp32 out; overwrites dead xb/weights)
  gemm_bt<0><<<dim3(NN / 128, NN / 128, BB), 256, 0, stream>>>(
      qb, kb, nullptr, S, CC, CC, CC, NN, 1.f / 32.f, 0,
      (long)NN * CC, (long)NN * CC, (long)NN * NN);

  // 4) exact top-k + softmax -> P (f16, in place over S; row pitch 4096 f16)
  topk_softmax_kernel<<<MTOT, 256, 0, stream>>>(S);

  // 5) O[b] = P[b] Vt[b]^T  (fp32 out to d_out)
  gemm_bt<0><<<dim3(NN / 128, CC / 128, BB), 256, 0, stream>>>(
      (const f16*)S, vtb, nullptr, out, NN, 2 * NN, MTOT, CC, 1.f, 0,
      (long)NN * 2 * NN, (long)NN, (long)NN * CC);
}

// Round 4
// 484.009 us; speedup vs baseline: 1.1083x; 1.1052x over previous
//
#include <hip/hip_runtime.h>

typedef _Float16 f16;
typedef __attribute__((ext_vector_type(8))) _Float16 f16x8;
typedef __attribute__((ext_vector_type(4))) _Float16 f16x4;
typedef __attribute__((ext_vector_type(4))) float f32x4;

// Problem constants
constexpr int BB = 8;
constexpr int NN = 2048;
constexpr int CC = 1024;
constexpr int MTOT = BB * NN;     // 16384
constexpr int KKEEP = 1638;

// ---------------------------------------------------------------------------
// async 16B global -> LDS
// ---------------------------------------------------------------------------
__device__ __forceinline__ void gl_lds16(const void* g, void* l) {
  __builtin_amdgcn_global_load_lds((__attribute__((address_space(1))) void*)g,
                                   (__attribute__((address_space(3))) void*)l,
                                   16, 0, 0);
}

// ---------------------------------------------------------------------------
// fp32 -> fp16 conversion (vectorized float4 -> f16x4)
// ---------------------------------------------------------------------------
__global__ __launch_bounds__(256) void cvt_f32_f16(const float* __restrict__ s,
                                                   f16* __restrict__ d, int n4) {
  int i = blockIdx.x * 256 + threadIdx.x;
  if (i < n4) {
    float4 f = ((const float4*)s)[i];
    f16x4 o = {(f16)f.x, (f16)f.y, (f16)f.z, (f16)f.w};
    ((f16x4*)d)[i] = o;
  }
}

// ---------------------------------------------------------------------------
// GEMM-BT core:  C[m][n] = sum_k A[m][k] * B[n][k]   (both operands k-contig)
// 128x128 tile, BK=32, 256 threads = 4 waves (2x2), each wave 64x64 = 4x4
// fragments of mfma_f32_16x16x32_f16.
// MODE 0: fp32 out, * scale               (S and PV GEMMs)
// MODE 1: f16 out, + bias[n]              (Q, K projections)
// MODE 2: f16 out transposed Ct[n][m], + bias[n]  (V projection -> Vt)
// ---------------------------------------------------------------------------
template <int MODE>
__global__ __launch_bounds__(256, 2) void gemm_bt(
    const f16* __restrict__ A, const f16* __restrict__ B,
    const float* __restrict__ bias, void* __restrict__ Cout,
    int K, int lda, int ldb, int ldc, float scale, int ldct,
    long strideA, long strideB, long strideC) {
  const f16* Ab = A + (size_t)blockIdx.z * strideA;
  const f16* Bbp = B + (size_t)blockIdx.z * strideB;

  const int bm = blockIdx.x * 128;
  const int bn = blockIdx.y * 128;
  const int tid = threadIdx.x;
  const int wave = tid >> 6;
  const int lane = tid & 63;
  const int wy = wave >> 1, wx = wave & 1;

  __shared__ f16 As[128 * 32];
  __shared__ f16 Bs[128 * 32];

  f32x4 acc[4][4];
#pragma unroll
  for (int i = 0; i < 4; i++)
#pragma unroll
    for (int j = 0; j < 4; j++) acc[i][j] = (f32x4){0.f, 0.f, 0.f, 0.f};

  const int sr = wave * 32 + (lane >> 2);
  const int sc = (lane & 3) * 8;
  const f16* gA0 = Ab + (size_t)(bm + sr) * lda + sc;
  const f16* gA1 = gA0 + (size_t)16 * lda;
  const f16* gB0 = Bbp + (size_t)(bn + sr) * ldb + sc;
  const f16* gB1 = gB0 + (size_t)16 * ldb;
  f16* lA0 = As + (wave * 32) * 32;
  f16* lA1 = As + (wave * 32 + 16) * 32;
  f16* lB0 = Bs + (wave * 32) * 32;
  f16* lB1 = Bs + (wave * 32 + 16) * 32;

  const int frm = wy * 64 + (lane & 15);
  const int frn = wx * 64 + (lane & 15);
  const int kq = (lane >> 4) * 8;

  for (int k0 = 0; k0 < K; k0 += 32) {
    gl_lds16(gA0 + k0, lA0);
    gl_lds16(gA1 + k0, lA1);
    gl_lds16(gB0 + k0, lB0);
    gl_lds16(gB1 + k0, lB1);
    __syncthreads();
    f16x8 av[4], bv[4];
#pragma unroll
    for (int i = 0; i < 4; i++)
      av[i] = *(const f16x8*)(As + (frm + 16 * i) * 32 + kq);
#pragma unroll
    for (int i = 0; i < 4; i++)
      bv[i] = *(const f16x8*)(Bs + (frn + 16 * i) * 32 + kq);
#pragma unroll
    for (int i = 0; i < 4; i++)
#pragma unroll
      for (int j = 0; j < 4; j++)
        acc[i][j] =
            __builtin_amdgcn_mfma_f32_16x16x32_f16(av[i], bv[j], acc[i][j], 0, 0, 0);
    __syncthreads();
  }

  const int q = lane >> 4;
  const int ci = lane & 15;
#pragma unroll
  for (int i = 0; i < 4; i++) {
#pragma unroll
    for (int j = 0; j < 4; j++) {
      const int row0 = bm + wy * 64 + i * 16 + q * 4;
      const int col = bn + wx * 64 + j * 16 + ci;
      if (MODE == 0) {
        float* C = (float*)Cout + (size_t)blockIdx.z * strideC;
#pragma unroll
        for (int r = 0; r < 4; r++)
          C[(size_t)(row0 + r) * ldc + col] = acc[i][j][r] * scale;
      } else if (MODE == 1) {
        f16* C = (f16*)Cout + (size_t)blockIdx.z * strideC;
        const float bb = bias[col];
#pragma unroll
        for (int r = 0; r < 4; r++)
          C[(size_t)(row0 + r) * ldc + col] = (f16)(acc[i][j][r] + bb);
      } else {
        f16* C = (f16*)Cout;
        const float bb = bias[col];
        f16x4 o;
#pragma unroll
        for (int r = 0; r < 4; r++) o[r] = (f16)(acc[i][j][r] + bb);
        *(f16x4*)(C + (size_t)col * ldct + row0) = o;
      }
    }
  }
}

// ---------------------------------------------------------------------------
// Per-row exact top-k(1638) + softmax. One block (256 thr = 4 waves) per row.
// Thread t owns contiguous elements [8t, 8t+8).
// R4 algorithm: quantize to 11-bit monotone keys -> ONE 2048-bin histogram
// (atomics spread over ~600 bins, near-conflict-free) -> suffix scan finds
// threshold bin -> exact tie refinement among the (~2-6) elements in that bin
// on full fp32 value + index (matches lax.top_k stable tie-break; equal
// values always share a bin). Row max doubles as softmax max (always kept).
// Reads fp32 S, writes COMPACT f16 P (pitch 2048) to a separate buffer.
// ---------------------------------------------------------------------------
__global__ __launch_bounds__(256) void topk_softmax_kernel(
    const float* __restrict__ S, f16* __restrict__ P) {
  const size_t row = blockIdx.x;
  const float* srow = S + row * 2048;
  f16* prow = P + row * 2048;
  const int t = threadIdx.x;
  const int lane = t & 63;
  const int wave = t >> 6;

  float v[8];
  float4 f0 = ((const float4*)srow)[2 * t];
  float4 f1 = ((const float4*)srow)[2 * t + 1];
  v[0] = f0.x; v[1] = f0.y; v[2] = f0.z; v[3] = f0.w;
  v[4] = f1.x; v[5] = f1.y; v[6] = f1.z; v[7] = f1.w;

  __shared__ float wlo[4], whi[4];
  __shared__ float wf[4];
  __shared__ int wagg[4];
  __shared__ int hist[2048];
  __shared__ float cval[128];
  __shared__ int cidx[128];
  __shared__ int cnum;
  __shared__ int sh_thr, sh_want;

  // row min/max (hi is also the softmax max: the row max is always kept)
  float lo = v[0], hi = v[0];
#pragma unroll
  for (int j = 1; j < 8; j++) { lo = fminf(lo, v[j]); hi = fmaxf(hi, v[j]); }
#pragma unroll
  for (int off = 32; off > 0; off >>= 1) {
    lo = fminf(lo, __shfl_xor(lo, off, 64));
    hi = fmaxf(hi, __shfl_xor(hi, off, 64));
  }
  if (lane == 0) { wlo[wave] = lo; whi[wave] = hi; }
  if (t == 0) cnum = 0;
  // zero histogram: 256 threads x 8 bins
  ((int4*)hist)[2 * t] = (int4){0, 0, 0, 0};
  ((int4*)hist)[2 * t + 1] = (int4){0, 0, 0, 0};
  __syncthreads();
  lo = fminf(fminf(wlo[0], wlo[1]), fminf(wlo[2], wlo[3]));
  hi = fmaxf(fmaxf(whi[0], whi[1]), fmaxf(whi[2], whi[3]));

  if (hi == lo) {  // degenerate: all equal -> keep first KKEEP by index
    const float w = 1.0f / (float)KKEEP;
    f16x8 o;
#pragma unroll
    for (int j = 0; j < 8; j++) o[j] = (f16)((t * 8 + j < KKEEP) ? w : 0.f);
    *(f16x8*)(prow + t * 8) = o;
    return;
  }

  // quantize: monotone non-decreasing key in [0, 2047]
  const float qs = 2048.0f / (hi - lo);
  int key[8];
#pragma unroll
  for (int j = 0; j < 8; j++) {
    int k = (int)((v[j] - lo) * qs);
    key[j] = (k > 2047) ? 2047 : k;
  }
#pragma unroll
  for (int j = 0; j < 8; j++) atomicAdd(&hist[key[j]], 1);
  __syncthreads();

  // suffix scan over 2048 bins; thread t owns bins [8t, 8t+8)
  int4 h0 = ((const int4*)hist)[2 * t];
  int4 h1 = ((const int4*)hist)[2 * t + 1];
  int h[8] = {h0.x, h0.y, h0.z, h0.w, h1.x, h1.y, h1.z, h1.w};
  int s[8];
  s[7] = h[7];
#pragma unroll
  for (int j = 6; j >= 0; j--) s[j] = s[j + 1] + h[j];
  const int partial = s[0];
  int sfx = partial;  // wave suffix-inclusive over thread partials
#pragma unroll
  for (int off = 1; off < 64; off <<= 1) {
    int o = __shfl_down(sfx, off, 64);
    sfx += (lane + off < 64) ? o : 0;
  }
  if (lane == 0) wagg[wave] = sfx;
  __syncthreads();
  int hiw = 0;
#pragma unroll
  for (int w = 0; w < 4; w++) hiw += (w > wave) ? wagg[w] : 0;
  const int base = (sfx - partial) + hiw;  // sum over bins >= 8(t+1)
#pragma unroll
  for (int j = 0; j < 8; j++) {
    const int cum = s[j] + base;       // count of elements in bins >= 8t+j
    const int above = cum - h[j];      // bins > 8t+j
    if (cum >= KKEEP && above < KKEEP) {
      sh_thr = 8 * t + j;
      sh_want = KKEEP - above;
    }
  }
  __syncthreads();
  const int thr = sh_thr;
  const int wantin = sh_want;

  // collect threshold-bin candidates (expected ~2-6; cap 128)
#pragma unroll
  for (int j = 0; j < 8; j++) {
    if (key[j] == thr) {
      int slot = atomicAdd(&cnum, 1);
      if (slot < 128) { cval[slot] = v[j]; cidx[slot] = t * 8 + j; }
    }
  }
  __syncthreads();
  const int n = (cnum < 128) ? cnum : 128;

  // keep decision + exp + sum (mx = hi)
  float e[8];
  float lsum = 0.f;
#pragma unroll
  for (int j = 0; j < 8; j++) {
    bool kept;
    if (key[j] > thr) {
      kept = true;
    } else if (key[j] < thr) {
      kept = false;
    } else {
      // exact rank among bin candidates: (value desc, index asc)
      const int myidx = t * 8 + j;
      int rank = 0;
      for (int c = 0; c < n; c++) {
        const float cv = cval[c];
        rank += (cv > v[j] || (cv == v[j] && cidx[c] < myidx)) ? 1 : 0;
      }
      kept = rank < wantin;
    }
    e[j] = kept ? __expf(v[j] - hi) : 0.f;
    lsum += e[j];
  }
#pragma unroll
  for (int off = 32; off > 0; off >>= 1) lsum += __shfl_xor(lsum, off, 64);
  if (lane == 0) wf[wave] = lsum;
  __syncthreads();
  const float inv = 1.0f / (wf[0] + wf[1] + wf[2] + wf[3]);

  f16x8 o;
#pragma unroll
  for (int j = 0; j < 8; j++) o[j] = (f16)(e[j] * inv);
  *(f16x8*)(prow + t * 8) = o;
}

// ---------------------------------------------------------------------------
// launch
//
// Workspace layout (peak 224 MiB):
//   [qb 32M][kb 32M][vtb 32M][S fp32 128M]
// xb (32M) + f16 weights (6M) aliased into S's span (dead before S written).
// P (compact f16, 64M) aliased over [qb|kb] (dead after score GEMM).
// ---------------------------------------------------------------------------
extern "C" void kernel_launch(void* const* d_in, const int* in_sizes, int n_in,
                              void* d_out, int out_size, void* d_ws, size_t ws_size,
                              hipStream_t stream) {
  (void)in_sizes; (void)n_in; (void)out_size; (void)ws_size;
  const float* x = (const float*)d_in[0];
  const float* Wq = (const float*)d_in[1];
  const float* bq = (const float*)d_in[2];
  const float* Wk = (const float*)d_in[3];
  const float* bk = (const float*)d_in[4];
  const float* Wv = (const float*)d_in[5];
  const float* bv = (const float*)d_in[6];
  float* out = (float*)d_out;

  char* ws = (char*)d_ws;
  f16* qb = (f16*)(ws + 0);            // [16384][1024]  33,554,432 B
  f16* kb = (f16*)(ws + 33554432);     // [16384][1024]
  f16* vtb = (f16*)(ws + 67108864);    // [1024][16384] (V^T)
  float* S = (float*)(ws + 100663296); // [8][2048][2048] fp32 (134,217,728 B)
  // --- aliased into S's span; dead before S is first written ---
  f16* xb = (f16*)(ws + 100663296);    // [16384][1024]
  f16* wqb = (f16*)(ws + 134217728);
  f16* wkb = (f16*)(ws + 136314880);
  f16* wvb = (f16*)(ws + 138412032);
  // --- aliased over qb+kb; they are dead after the score GEMM ---
  f16* Pc = (f16*)(ws + 0);            // [8][2048][2048] f16 compact (64 MiB)

  // 1) conversions to fp16
  cvt_f32_f16<<<(MTOT * CC / 4 + 255) / 256, 256, 0, stream>>>(x, xb, MTOT * CC / 4);
  cvt_f32_f16<<<(CC * CC / 4 + 255) / 256, 256, 0, stream>>>(Wq, wqb, CC * CC / 4);
  cvt_f32_f16<<<(CC * CC / 4 + 255) / 256, 256, 0, stream>>>(Wk, wkb, CC * CC / 4);
  cvt_f32_f16<<<(CC * CC / 4 + 255) / 256, 256, 0, stream>>>(Wv, wvb, CC * CC / 4);

  // 2) projections: Q, K (row-major f16) and V stored transposed Vt[1024][16384]
  gemm_bt<1><<<dim3(MTOT / 128, CC / 128, 1), 256, 0, stream>>>(
      xb, wqb, bq, qb, CC, CC, CC, CC, 1.f, 0, 0, 0, 0);
  gemm_bt<1><<<dim3(MTOT / 128, CC / 128, 1), 256, 0, stream>>>(
      xb, wkb, bk, kb, CC, CC, CC, CC, 1.f, 0, 0, 0, 0);
  gemm_bt<2><<<dim3(MTOT / 128, CC / 128, 1), 256, 0, stream>>>(
      xb, wvb, bv, vtb, CC, CC, CC, 0, 1.f, MTOT, 0, 0, 0);

  // 3) scores S[b] = Q[b] K[b]^T / 32  (fp32 out; overwrites dead xb/weights)
  gemm_bt<0><<<dim3(NN / 128, NN / 128, BB), 256, 0, stream>>>(
      qb, kb, nullptr, S, CC, CC, CC, NN, 1.f / 32.f, 0,
      (long)NN * CC, (long)NN * CC, (long)NN * NN);

  // 4) exact top-k + softmax -> compact P f16 (over dead qb|kb)
  topk_softmax_kernel<<<MTOT, 256, 0, stream>>>(S, Pc);

  // 5) O[b] = P[b] Vt[b]^T  (fp32 out to d_out)
  gemm_bt<0><<<dim3(NN / 128, CC / 128, BB), 256, 0, stream>>>(
      Pc, vtb, nullptr, out, NN, NN, MTOT, CC, 1.f, 0,
      (long)NN * NN, (long)NN, (long)NN * CC);
}

// Round 5
// 457.047 us; speedup vs baseline: 1.1737x; 1.0590x over previous
//
#include <hip/hip_runtime.h>

typedef _Float16 f16;
typedef __attribute__((ext_vector_type(8))) _Float16 f16x8;
typedef __attribute__((ext_vector_type(4))) _Float16 f16x4;
typedef __attribute__((ext_vector_type(4))) float f32x4;

// Problem constants
constexpr int BB = 8;
constexpr int NN = 2048;
constexpr int CC = 1024;
constexpr int MTOT = BB * NN;     // 16384
constexpr int KKEEP = 1638;

// ---------------------------------------------------------------------------
// async 16B global -> LDS (HW: dst = wave-uniform base + lane*16)
// ---------------------------------------------------------------------------
__device__ __forceinline__ void gl_lds16(const void* g, void* l) {
  __builtin_amdgcn_global_load_lds((__attribute__((address_space(1))) void*)g,
                                   (__attribute__((address_space(3))) void*)l,
                                   16, 0, 0);
}

// ---------------------------------------------------------------------------
// Unified fp32 -> fp16 conversion: x -> xb, {Wq,Wk,Wv} -> wqkv (concatenated)
// ---------------------------------------------------------------------------
constexpr int X4 = MTOT * CC / 4;   // 4,194,304 vec4
constexpr int W4 = CC * CC / 4;     // 262,144 vec4
__global__ __launch_bounds__(256) void cvt_all(
    const float* __restrict__ x, const float* __restrict__ Wq,
    const float* __restrict__ Wk, const float* __restrict__ Wv,
    f16* __restrict__ xb, f16* __restrict__ wqkv) {
  int i = blockIdx.x * 256 + threadIdx.x;
  const float* s;
  f16* d;
  if (i < X4) { s = x; d = xb; }
  else if (i < X4 + W4) { i -= X4; s = Wq; d = wqkv; }
  else if (i < X4 + 2 * W4) { i -= X4 + W4; s = Wk; d = wqkv + CC * CC; }
  else { i -= X4 + 2 * W4; s = Wv; d = wqkv + 2 * CC * CC; }
  float4 f = ((const float4*)s)[i];
  f16x4 o = {(f16)f.x, (f16)f.y, (f16)f.z, (f16)f.w};
  ((f16x4*)d)[i] = o;
}

// ---------------------------------------------------------------------------
// GEMM-BT core:  C[m][n] = sum_k A[m][k] * B[n][k]   (both operands k-contig)
// 128x128 tile, BK=64 (32 KB LDS), 256 threads = 4 waves (2x2), each wave
// 64x64 = 4x4 fragments of mfma_f32_16x16x32_f16, 32 MFMA per barrier pair.
//
// LDS k-granule XOR swizzle: global_load_lds forces LDS dst = base + lane*16,
// so instead of padding we rotate WHICH global 16B k-granule each lane loads:
// LDS[row][g] holds global granule g ^ (4*(row&1)). Fragment reads XOR the
// same term. This spreads the 128B-row-stride reads over all 32 banks
// (8 dwords/bank per wave read = conflict-free); without it every quad would
// hit one 4-bank group (16-way).
//
// MODE 0: fp32 out, * scale, batched (score S and PV GEMMs)
// MODE 3: fused QKV epilogue: cols [0,2048) -> f16 row-major QK (pitch 2048,
//         bias bq/bk), cols [2048,3072) -> f16 TRANSPOSED Vt[1024][MTOT] +bv.
// ---------------------------------------------------------------------------
template <int MODE>
__global__ __launch_bounds__(256, 2) void gemm_bt(
    const f16* __restrict__ A, const f16* __restrict__ B,
    const float* __restrict__ b0, const float* __restrict__ b1,
    const float* __restrict__ b2, void* __restrict__ Cout,
    void* __restrict__ Cout2, int K, int lda, int ldb, int ldc, float scale,
    long strideA, long strideB, long strideC) {
  const f16* Ab = A + (size_t)blockIdx.z * strideA;
  const f16* Bbp = B + (size_t)blockIdx.z * strideB;

  const int bm = blockIdx.x * 128;
  const int bn = blockIdx.y * 128;
  const int tid = threadIdx.x;
  const int wave = tid >> 6;
  const int lane = tid & 63;
  const int wy = wave >> 1, wx = wave & 1;

  __shared__ f16 As[128 * 64];
  __shared__ f16 Bs[128 * 64];

  f32x4 acc[4][4];
#pragma unroll
  for (int i = 0; i < 4; i++)
#pragma unroll
    for (int j = 0; j < 4; j++) acc[i][j] = (f32x4){0.f, 0.f, 0.f, 0.f};

  // staging: wave w covers tile rows [w*32, w*32+32), 4 insts x 8 rows.
  // lane l -> row (l>>3), granule (l&7); loads global granule swizzled.
  const int sr = wave * 32 + (lane >> 3);
  const int gsrc = ((lane & 7) ^ (((lane >> 3) & 1) << 2)) * 8;
  const f16* gA0 = Ab + (size_t)(bm + sr) * lda + gsrc;
  const f16* gB0 = Bbp + (size_t)(bn + sr) * ldb + gsrc;
  f16* lA = As + (wave * 32) * 64 + lane * 8;  // == base + lane*16B
  f16* lB = Bs + (wave * 32) * 64 + lane * 8;

  // fragment coords: A[m = frm0 + 16i][k = kq + j + 32*kk]
  const int id = lane & 15;
  const int q = lane >> 4;
  const int frm0 = wy * 64 + id;
  const int frn0 = wx * 64 + id;
  const int sw = (id & 1) << 2;
  const int g0 = (q ^ sw) * 8;          // LDS granule offset for kk=0
  const int g1 = ((q + 4) ^ sw) * 8;    // for kk=1

  for (int k0 = 0; k0 < K; k0 += 64) {
#pragma unroll
    for (int r = 0; r < 4; r++) {
      gl_lds16(gA0 + (size_t)8 * r * lda + k0, lA + r * 512);
      gl_lds16(gB0 + (size_t)8 * r * ldb + k0, lB + r * 512);
    }
    __syncthreads();
    f16x8 av[2][4], bv[2][4];
#pragma unroll
    for (int i = 0; i < 4; i++) {
      av[0][i] = *(const f16x8*)(As + (frm0 + 16 * i) * 64 + g0);
      av[1][i] = *(const f16x8*)(As + (frm0 + 16 * i) * 64 + g1);
      bv[0][i] = *(const f16x8*)(Bs + (frn0 + 16 * i) * 64 + g0);
      bv[1][i] = *(const f16x8*)(Bs + (frn0 + 16 * i) * 64 + g1);
    }
#pragma unroll
    for (int kk = 0; kk < 2; kk++)
#pragma unroll
      for (int i = 0; i < 4; i++)
#pragma unroll
        for (int j = 0; j < 4; j++)
          acc[i][j] = __builtin_amdgcn_mfma_f32_16x16x32_f16(av[kk][i], bv[kk][j],
                                                             acc[i][j], 0, 0, 0);
    __syncthreads();
  }

  // epilogue: C/D layout col=lane&15, row=(lane>>4)*4 + r
  const int ci = id;
#pragma unroll
  for (int i = 0; i < 4; i++) {
#pragma unroll
    for (int j = 0; j < 4; j++) {
      const int row0 = bm + wy * 64 + i * 16 + q * 4;
      const int col = bn + wx * 64 + j * 16 + ci;
      if (MODE == 0) {
        float* C = (float*)Cout + (size_t)blockIdx.z * strideC;
#pragma unroll
        for (int r = 0; r < 4; r++)
          C[(size_t)(row0 + r) * ldc + col] = acc[i][j][r] * scale;
      } else {  // MODE 3 — region is uniform per block (bn multiple of 128)
        if (bn < 2048) {
          f16* C = (f16*)Cout;
          const float* bias = (bn < 1024) ? b0 : (b1 - 1024);
          const float bb = bias[col];
#pragma unroll
          for (int r = 0; r < 4; r++)
            C[(size_t)(row0 + r) * 2048 + col] = (f16)(acc[i][j][r] + bb);
        } else {
          f16* C = (f16*)Cout2;
          const float bb = b2[col - 2048];
          f16x4 o;
#pragma unroll
          for (int r = 0; r < 4; r++) o[r] = (f16)(acc[i][j][r] + bb);
          *(f16x4*)(C + (size_t)(col - 2048) * MTOT + row0) = o;
        }
      }
    }
  }
}

// ---------------------------------------------------------------------------
// Per-row exact top-k(1638) + softmax (unchanged from R4).
// Quantized 2048-bin histogram -> threshold bin -> exact tie refinement on
// fp32 value + index. Reads fp32 S (pitch 2048), writes compact f16 P.
// ---------------------------------------------------------------------------
__global__ __launch_bounds__(256) void topk_softmax_kernel(
    const float* __restrict__ S, f16* __restrict__ P) {
  const size_t row = blockIdx.x;
  const float* srow = S + row * 2048;
  f16* prow = P + row * 2048;
  const int t = threadIdx.x;
  const int lane = t & 63;
  const int wave = t >> 6;

  float v[8];
  float4 f0 = ((const float4*)srow)[2 * t];
  float4 f1 = ((const float4*)srow)[2 * t + 1];
  v[0] = f0.x; v[1] = f0.y; v[2] = f0.z; v[3] = f0.w;
  v[4] = f1.x; v[5] = f1.y; v[6] = f1.z; v[7] = f1.w;

  __shared__ float wlo[4], whi[4];
  __shared__ float wf[4];
  __shared__ int wagg[4];
  __shared__ int hist[2048];
  __shared__ float cval[128];
  __shared__ int cidx[128];
  __shared__ int cnum;
  __shared__ int sh_thr, sh_want;

  float lo = v[0], hi = v[0];
#pragma unroll
  for (int j = 1; j < 8; j++) { lo = fminf(lo, v[j]); hi = fmaxf(hi, v[j]); }
#pragma unroll
  for (int off = 32; off > 0; off >>= 1) {
    lo = fminf(lo, __shfl_xor(lo, off, 64));
    hi = fmaxf(hi, __shfl_xor(hi, off, 64));
  }
  if (lane == 0) { wlo[wave] = lo; whi[wave] = hi; }
  if (t == 0) cnum = 0;
  ((int4*)hist)[2 * t] = (int4){0, 0, 0, 0};
  ((int4*)hist)[2 * t + 1] = (int4){0, 0, 0, 0};
  __syncthreads();
  lo = fminf(fminf(wlo[0], wlo[1]), fminf(wlo[2], wlo[3]));
  hi = fmaxf(fmaxf(whi[0], whi[1]), fmaxf(whi[2], whi[3]));

  if (hi == lo) {
    const float w = 1.0f / (float)KKEEP;
    f16x8 o;
#pragma unroll
    for (int j = 0; j < 8; j++) o[j] = (f16)((t * 8 + j < KKEEP) ? w : 0.f);
    *(f16x8*)(prow + t * 8) = o;
    return;
  }

  const float qs = 2048.0f / (hi - lo);
  int key[8];
#pragma unroll
  for (int j = 0; j < 8; j++) {
    int k = (int)((v[j] - lo) * qs);
    key[j] = (k > 2047) ? 2047 : k;
  }
#pragma unroll
  for (int j = 0; j < 8; j++) atomicAdd(&hist[key[j]], 1);
  __syncthreads();

  int4 h0 = ((const int4*)hist)[2 * t];
  int4 h1 = ((const int4*)hist)[2 * t + 1];
  int h[8] = {h0.x, h0.y, h0.z, h0.w, h1.x, h1.y, h1.z, h1.w};
  int s[8];
  s[7] = h[7];
#pragma unroll
  for (int j = 6; j >= 0; j--) s[j] = s[j + 1] + h[j];
  const int partial = s[0];
  int sfx = partial;
#pragma unroll
  for (int off = 1; off < 64; off <<= 1) {
    int o = __shfl_down(sfx, off, 64);
    sfx += (lane + off < 64) ? o : 0;
  }
  if (lane == 0) wagg[wave] = sfx;
  __syncthreads();
  int hiw = 0;
#pragma unroll
  for (int w = 0; w < 4; w++) hiw += (w > wave) ? wagg[w] : 0;
  const int base = (sfx - partial) + hiw;
#pragma unroll
  for (int j = 0; j < 8; j++) {
    const int cum = s[j] + base;
    const int above = cum - h[j];
    if (cum >= KKEEP && above < KKEEP) {
      sh_thr = 8 * t + j;
      sh_want = KKEEP - above;
    }
  }
  __syncthreads();
  const int thr = sh_thr;
  const int wantin = sh_want;

#pragma unroll
  for (int j = 0; j < 8; j++) {
    if (key[j] == thr) {
      int slot = atomicAdd(&cnum, 1);
      if (slot < 128) { cval[slot] = v[j]; cidx[slot] = t * 8 + j; }
    }
  }
  __syncthreads();
  const int n = (cnum < 128) ? cnum : 128;

  float e[8];
  float lsum = 0.f;
#pragma unroll
  for (int j = 0; j < 8; j++) {
    bool kept;
    if (key[j] > thr) {
      kept = true;
    } else if (key[j] < thr) {
      kept = false;
    } else {
      const int myidx = t * 8 + j;
      int rank = 0;
      for (int c = 0; c < n; c++) {
        const float cv = cval[c];
        rank += (cv > v[j] || (cv == v[j] && cidx[c] < myidx)) ? 1 : 0;
      }
      kept = rank < wantin;
    }
    e[j] = kept ? __expf(v[j] - hi) : 0.f;
    lsum += e[j];
  }
#pragma unroll
  for (int off = 32; off > 0; off >>= 1) lsum += __shfl_xor(lsum, off, 64);
  if (lane == 0) wf[wave] = lsum;
  __syncthreads();
  const float inv = 1.0f / (wf[0] + wf[1] + wf[2] + wf[3]);

  f16x8 o;
#pragma unroll
  for (int j = 0; j < 8; j++) o[j] = (f16)(e[j] * inv);
  *(f16x8*)(prow + t * 8) = o;
}

// ---------------------------------------------------------------------------
// launch — 5 dispatches.
// Workspace (peak 224 MiB): [qkb 64M][vtb 32M][S fp32 128M]
//   qkb = [16384][2048] f16: cols 0-1023 Q, 1024-2047 K (score GEMM uses
//   lda=ldb=2048 with B offset +1024).
//   xb (32M) + wqkv (6M) aliased into S's span (dead before S written).
//   Pc (compact f16 P, 64M) aliased over qkb (dead after score GEMM).
// ---------------------------------------------------------------------------
extern "C" void kernel_launch(void* const* d_in, const int* in_sizes, int n_in,
                              void* d_out, int out_size, void* d_ws, size_t ws_size,
                              hipStream_t stream) {
  (void)in_sizes; (void)n_in; (void)out_size; (void)ws_size;
  const float* x = (const float*)d_in[0];
  const float* Wq = (const float*)d_in[1];
  const float* bq = (const float*)d_in[2];
  const float* Wk = (const float*)d_in[3];
  const float* bk = (const float*)d_in[4];
  const float* Wv = (const float*)d_in[5];
  const float* bv = (const float*)d_in[6];
  float* out = (float*)d_out;

  char* ws = (char*)d_ws;
  f16* qkb = (f16*)(ws + 0);           // [16384][2048] f16  67,108,864 B
  f16* vtb = (f16*)(ws + 67108864);    // [1024][16384] f16 (V^T)
  float* S = (float*)(ws + 100663296); // [8][2048][2048] fp32 (134,217,728 B)
  // --- aliased into S's span; dead before S is first written ---
  f16* xb = (f16*)(ws + 100663296);    // [16384][1024]
  f16* wqkv = (f16*)(ws + 134217728);  // [3072][1024] (Wq|Wk|Wv rows)
  // --- aliased over qkb; dead after the score GEMM ---
  f16* Pc = (f16*)(ws + 0);            // [8][2048][2048] f16 compact

  // 1) conversions (single dispatch)
  cvt_all<<<(X4 + 3 * W4 + 255) / 256, 256, 0, stream>>>(x, Wq, Wk, Wv, xb, wqkv);

  // 2) fused QKV projection: cols 0-2047 -> qkb, cols 2048-3071 -> vtb (transposed)
  gemm_bt<3><<<dim3(MTOT / 128, 3072 / 128, 1), 256, 0, stream>>>(
      xb, wqkv, bq, bk, bv, qkb, vtb, CC, CC, CC, 0, 1.f, 0, 0, 0);

  // 3) scores S[b] = Q[b] K[b]^T / 32  (fp32 out; overwrites dead xb/wqkv)
  gemm_bt<0><<<dim3(NN / 128, NN / 128, BB), 256, 0, stream>>>(
      qkb, qkb + 1024, nullptr, nullptr, nullptr, S, nullptr, CC, 2048, 2048, NN,
      1.f / 32.f, (long)NN * 2048, (long)NN * 2048, (long)NN * NN);

  // 4) exact top-k + softmax -> compact P f16 (over dead qkb)
  topk_softmax_kernel<<<MTOT, 256, 0, stream>>>(S, Pc);

  // 5) O[b] = P[b] Vt[b]^T  (fp32 out to d_out)
  gemm_bt<0><<<dim3(NN / 128, CC / 128, BB), 256, 0, stream>>>(
      Pc, vtb, nullptr, nullptr, nullptr, out, nullptr, NN, NN, MTOT, CC, 1.f,
      (long)NN * NN, (long)NN, (long)NN * CC);
}

// Round 6
// 435.458 us; speedup vs baseline: 1.2319x; 1.0496x over previous
//
#include <hip/hip_runtime.h>

typedef _Float16 f16;
typedef __attribute__((ext_vector_type(8))) _Float16 f16x8;
typedef __attribute__((ext_vector_type(4))) _Float16 f16x4;
typedef __attribute__((ext_vector_type(4))) float f32x4;

// Problem constants
constexpr int BB = 8;
constexpr int NN = 2048;
constexpr int CC = 1024;
constexpr int MTOT = BB * NN;     // 16384
constexpr int KKEEP = 1638;

// ---------------------------------------------------------------------------
// async 16B global -> LDS (HW: dst = wave-uniform base + lane*16)
// ---------------------------------------------------------------------------
__device__ __forceinline__ void gl_lds16(const void* g, void* l) {
  __builtin_amdgcn_global_load_lds((__attribute__((address_space(1))) void*)g,
                                   (__attribute__((address_space(3))) void*)l,
                                   16, 0, 0);
}

// ---------------------------------------------------------------------------
// Unified fp32 -> fp16 conversion: x -> xb, {Wq,Wk,Wv} -> wqkv (concatenated)
// ---------------------------------------------------------------------------
constexpr int X4 = MTOT * CC / 4;   // 4,194,304 vec4
constexpr int W4 = CC * CC / 4;     // 262,144 vec4
__global__ __launch_bounds__(256) void cvt_all(
    const float* __restrict__ x, const float* __restrict__ Wq,
    const float* __restrict__ Wk, const float* __restrict__ Wv,
    f16* __restrict__ xb, f16* __restrict__ wqkv) {
  int i = blockIdx.x * 256 + threadIdx.x;
  const float* s;
  f16* d;
  if (i < X4) { s = x; d = xb; }
  else if (i < X4 + W4) { i -= X4; s = Wq; d = wqkv; }
  else if (i < X4 + 2 * W4) { i -= X4 + W4; s = Wk; d = wqkv + CC * CC; }
  else { i -= X4 + 2 * W4; s = Wv; d = wqkv + 2 * CC * CC; }
  float4 f = ((const float4*)s)[i];
  f16x4 o = {(f16)f.x, (f16)f.y, (f16)f.z, (f16)f.w};
  ((f16x4*)d)[i] = o;
}

// ---------------------------------------------------------------------------
// GEMM-BT core:  C[m][n] = sum_k A[m][k] * B[n][k]   (both operands k-contig)
// 128x128 tile, BK=64 (32 KB LDS), 256 threads = 4 waves (2x2), each wave
// 64x64 = 4x4 fragments of mfma_f32_16x16x32_f16, 32 MFMA per barrier pair.
//
// LDS 3-bit row-XOR swizzle (R6): rows are 64 f16 = exactly 32 banks, so all
// rows alias bank-identically. global_load_lds pins LDS dst = base + lane*16,
// so we permute the SOURCE: LDS slot s of row R holds global k-granule
// s ^ (R&7). Staging lane l (row l>>3, slot l&7) therefore loads granule
// (l&7) ^ ((l>>3)&7). Fragment reads address slot (q+4kk) ^ (m&7); since
// m&7 == id&7, each consecutive-lane octet (fixed q, id 0..7) covers all 8
// bank-groups -> conflict-free ds_read_b128 phases. (R5's 1-bit XOR left a
// 4-way in-phase conflict: SQ_LDS_BANK_CONFLICT 3.8e7.)
//
// MODE 0: fp32 out, * scale, batched (score S and PV GEMMs)
// MODE 3: fused QKV epilogue: cols [0,2048) -> f16 row-major QK (pitch 2048,
//         bias bq/bk), cols [2048,3072) -> f16 TRANSPOSED Vt[1024][MTOT] +bv.
// ---------------------------------------------------------------------------
template <int MODE>
__global__ __launch_bounds__(256, 2) void gemm_bt(
    const f16* __restrict__ A, const f16* __restrict__ B,
    const float* __restrict__ b0, const float* __restrict__ b1,
    const float* __restrict__ b2, void* __restrict__ Cout,
    void* __restrict__ Cout2, int K, int lda, int ldb, int ldc, float scale,
    long strideA, long strideB, long strideC) {
  const f16* Ab = A + (size_t)blockIdx.z * strideA;
  const f16* Bbp = B + (size_t)blockIdx.z * strideB;

  const int bm = blockIdx.x * 128;
  const int bn = blockIdx.y * 128;
  const int tid = threadIdx.x;
  const int wave = tid >> 6;
  const int lane = tid & 63;
  const int wy = wave >> 1, wx = wave & 1;

  __shared__ f16 As[128 * 64];
  __shared__ f16 Bs[128 * 64];

  f32x4 acc[4][4];
#pragma unroll
  for (int i = 0; i < 4; i++)
#pragma unroll
    for (int j = 0; j < 4; j++) acc[i][j] = (f32x4){0.f, 0.f, 0.f, 0.f};

  // staging: wave w covers tile rows [w*32, w*32+32), 4 insts x 8 rows.
  // lane l -> row (l>>3), loads global granule (l&7)^((l>>3)&7).
  const int sr = wave * 32 + (lane >> 3);
  const int gsrc = ((lane & 7) ^ ((lane >> 3) & 7)) * 8;
  const f16* gA0 = Ab + (size_t)(bm + sr) * lda + gsrc;
  const f16* gB0 = Bbp + (size_t)(bn + sr) * ldb + gsrc;
  f16* lA = As + (wave * 32) * 64 + lane * 8;  // == base + lane*16B
  f16* lB = Bs + (wave * 32) * 64 + lane * 8;

  // fragment coords: A[m][k granule q+4kk] lives at LDS slot (q+4kk)^(m&7)
  const int id = lane & 15;
  const int q = lane >> 4;
  const int frm0 = wy * 64 + id;
  const int frn0 = wx * 64 + id;
  const int g0 = (q ^ (id & 7)) * 8;        // slot offset (f16) for kk=0
  const int g1 = ((q + 4) ^ (id & 7)) * 8;  // for kk=1

  for (int k0 = 0; k0 < K; k0 += 64) {
#pragma unroll
    for (int r = 0; r < 4; r++) {
      gl_lds16(gA0 + (size_t)8 * r * lda + k0, lA + r * 512);
      gl_lds16(gB0 + (size_t)8 * r * ldb + k0, lB + r * 512);
    }
    __syncthreads();
    f16x8 av[2][4], bv[2][4];
#pragma unroll
    for (int i = 0; i < 4; i++) {
      av[0][i] = *(const f16x8*)(As + (frm0 + 16 * i) * 64 + g0);
      av[1][i] = *(const f16x8*)(As + (frm0 + 16 * i) * 64 + g1);
      bv[0][i] = *(const f16x8*)(Bs + (frn0 + 16 * i) * 64 + g0);
      bv[1][i] = *(const f16x8*)(Bs + (frn0 + 16 * i) * 64 + g1);
    }
#pragma unroll
    for (int kk = 0; kk < 2; kk++)
#pragma unroll
      for (int i = 0; i < 4; i++)
#pragma unroll
        for (int j = 0; j < 4; j++)
          acc[i][j] = __builtin_amdgcn_mfma_f32_16x16x32_f16(av[kk][i], bv[kk][j],
                                                             acc[i][j], 0, 0, 0);
    __syncthreads();
  }

  // epilogue: C/D layout col=lane&15, row=(lane>>4)*4 + r
  const int ci = id;
#pragma unroll
  for (int i = 0; i < 4; i++) {
#pragma unroll
    for (int j = 0; j < 4; j++) {
      const int row0 = bm + wy * 64 + i * 16 + q * 4;
      const int col = bn + wx * 64 + j * 16 + ci;
      if (MODE == 0) {
        float* C = (float*)Cout + (size_t)blockIdx.z * strideC;
#pragma unroll
        for (int r = 0; r < 4; r++)
          C[(size_t)(row0 + r) * ldc + col] = acc[i][j][r] * scale;
      } else {  // MODE 3 — region is uniform per block (bn multiple of 128)
        if (bn < 2048) {
          f16* C = (f16*)Cout;
          const float* bias = (bn < 1024) ? b0 : (b1 - 1024);
          const float bb = bias[col];
#pragma unroll
          for (int r = 0; r < 4; r++)
            C[(size_t)(row0 + r) * 2048 + col] = (f16)(acc[i][j][r] + bb);
        } else {
          f16* C = (f16*)Cout2;
          const float bb = b2[col - 2048];
          f16x4 o;
#pragma unroll
          for (int r = 0; r < 4; r++) o[r] = (f16)(acc[i][j][r] + bb);
          *(f16x4*)(C + (size_t)(col - 2048) * MTOT + row0) = o;
        }
      }
    }
  }
}

// ---------------------------------------------------------------------------
// Per-row exact top-k(1638) + softmax (unchanged from R4).
// Quantized 2048-bin histogram -> threshold bin -> exact tie refinement on
// fp32 value + index. Reads fp32 S (pitch 2048), writes compact f16 P.
// ---------------------------------------------------------------------------
__global__ __launch_bounds__(256) void topk_softmax_kernel(
    const float* __restrict__ S, f16* __restrict__ P) {
  const size_t row = blockIdx.x;
  const float* srow = S + row * 2048;
  f16* prow = P + row * 2048;
  const int t = threadIdx.x;
  const int lane = t & 63;
  const int wave = t >> 6;

  float v[8];
  float4 f0 = ((const float4*)srow)[2 * t];
  float4 f1 = ((const float4*)srow)[2 * t + 1];
  v[0] = f0.x; v[1] = f0.y; v[2] = f0.z; v[3] = f0.w;
  v[4] = f1.x; v[5] = f1.y; v[6] = f1.z; v[7] = f1.w;

  __shared__ float wlo[4], whi[4];
  __shared__ float wf[4];
  __shared__ int wagg[4];
  __shared__ int hist[2048];
  __shared__ float cval[128];
  __shared__ int cidx[128];
  __shared__ int cnum;
  __shared__ int sh_thr, sh_want;

  float lo = v[0], hi = v[0];
#pragma unroll
  for (int j = 1; j < 8; j++) { lo = fminf(lo, v[j]); hi = fmaxf(hi, v[j]); }
#pragma unroll
  for (int off = 32; off > 0; off >>= 1) {
    lo = fminf(lo, __shfl_xor(lo, off, 64));
    hi = fmaxf(hi, __shfl_xor(hi, off, 64));
  }
  if (lane == 0) { wlo[wave] = lo; whi[wave] = hi; }
  if (t == 0) cnum = 0;
  ((int4*)hist)[2 * t] = (int4){0, 0, 0, 0};
  ((int4*)hist)[2 * t + 1] = (int4){0, 0, 0, 0};
  __syncthreads();
  lo = fminf(fminf(wlo[0], wlo[1]), fminf(wlo[2], wlo[3]));
  hi = fmaxf(fmaxf(whi[0], whi[1]), fmaxf(whi[2], whi[3]));

  if (hi == lo) {
    const float w = 1.0f / (float)KKEEP;
    f16x8 o;
#pragma unroll
    for (int j = 0; j < 8; j++) o[j] = (f16)((t * 8 + j < KKEEP) ? w : 0.f);
    *(f16x8*)(prow + t * 8) = o;
    return;
  }

  const float qs = 2048.0f / (hi - lo);
  int key[8];
#pragma unroll
  for (int j = 0; j < 8; j++) {
    int k = (int)((v[j] - lo) * qs);
    key[j] = (k > 2047) ? 2047 : k;
  }
#pragma unroll
  for (int j = 0; j < 8; j++) atomicAdd(&hist[key[j]], 1);
  __syncthreads();

  int4 h0 = ((const int4*)hist)[2 * t];
  int4 h1 = ((const int4*)hist)[2 * t + 1];
  int h[8] = {h0.x, h0.y, h0.z, h0.w, h1.x, h1.y, h1.z, h1.w};
  int s[8];
  s[7] = h[7];
#pragma unroll
  for (int j = 6; j >= 0; j--) s[j] = s[j + 1] + h[j];
  const int partial = s[0];
  int sfx = partial;
#pragma unroll
  for (int off = 1; off < 64; off <<= 1) {
    int o = __shfl_down(sfx, off, 64);
    sfx += (lane + off < 64) ? o : 0;
  }
  if (lane == 0) wagg[wave] = sfx;
  __syncthreads();
  int hiw = 0;
#pragma unroll
  for (int w = 0; w < 4; w++) hiw += (w > wave) ? wagg[w] : 0;
  const int base = (sfx - partial) + hiw;
#pragma unroll
  for (int j = 0; j < 8; j++) {
    const int cum = s[j] + base;
    const int above = cum - h[j];
    if (cum >= KKEEP && above < KKEEP) {
      sh_thr = 8 * t + j;
      sh_want = KKEEP - above;
    }
  }
  __syncthreads();
  const int thr = sh_thr;
  const int wantin = sh_want;

#pragma unroll
  for (int j = 0; j < 8; j++) {
    if (key[j] == thr) {
      int slot = atomicAdd(&cnum, 1);
      if (slot < 128) { cval[slot] = v[j]; cidx[slot] = t * 8 + j; }
    }
  }
  __syncthreads();
  const int n = (cnum < 128) ? cnum : 128;

  float e[8];
  float lsum = 0.f;
#pragma unroll
  for (int j = 0; j < 8; j++) {
    bool kept;
    if (key[j] > thr) {
      kept = true;
    } else if (key[j] < thr) {
      kept = false;
    } else {
      const int myidx = t * 8 + j;
      int rank = 0;
      for (int c = 0; c < n; c++) {
        const float cv = cval[c];
        rank += (cv > v[j] || (cv == v[j] && cidx[c] < myidx)) ? 1 : 0;
      }
      kept = rank < wantin;
    }
    e[j] = kept ? __expf(v[j] - hi) : 0.f;
    lsum += e[j];
  }
#pragma unroll
  for (int off = 32; off > 0; off >>= 1) lsum += __shfl_xor(lsum, off, 64);
  if (lane == 0) wf[wave] = lsum;
  __syncthreads();
  const float inv = 1.0f / (wf[0] + wf[1] + wf[2] + wf[3]);

  f16x8 o;
#pragma unroll
  for (int j = 0; j < 8; j++) o[j] = (f16)(e[j] * inv);
  *(f16x8*)(prow + t * 8) = o;
}

// ---------------------------------------------------------------------------
// launch — 5 dispatches.
// Workspace (peak 224 MiB): [qkb 64M][vtb 32M][S fp32 128M]
//   qkb = [16384][2048] f16: cols 0-1023 Q, 1024-2047 K.
//   xb (32M) + wqkv (6M) aliased into S's span (dead before S written).
//   Pc (compact f16 P, 64M) aliased over qkb (dead after score GEMM).
// ---------------------------------------------------------------------------
extern "C" void kernel_launch(void* const* d_in, const int* in_sizes, int n_in,
                              void* d_out, int out_size, void* d_ws, size_t ws_size,
                              hipStream_t stream) {
  (void)in_sizes; (void)n_in; (void)out_size; (void)ws_size;
  const float* x = (const float*)d_in[0];
  const float* Wq = (const float*)d_in[1];
  const float* bq = (const float*)d_in[2];
  const float* Wk = (const float*)d_in[3];
  const float* bk = (const float*)d_in[4];
  const float* Wv = (const float*)d_in[5];
  const float* bv = (const float*)d_in[6];
  float* out = (float*)d_out;

  char* ws = (char*)d_ws;
  f16* qkb = (f16*)(ws + 0);           // [16384][2048] f16  67,108,864 B
  f16* vtb = (f16*)(ws + 67108864);    // [1024][16384] f16 (V^T)
  float* S = (float*)(ws + 100663296); // [8][2048][2048] fp32 (134,217,728 B)
  // --- aliased into S's span; dead before S is first written ---
  f16* xb = (f16*)(ws + 100663296);    // [16384][1024]
  f16* wqkv = (f16*)(ws + 134217728);  // [3072][1024] (Wq|Wk|Wv rows)
  // --- aliased over qkb; dead after the score GEMM ---
  f16* Pc = (f16*)(ws + 0);            // [8][2048][2048] f16 compact

  // 1) conversions (single dispatch)
  cvt_all<<<(X4 + 3 * W4 + 255) / 256, 256, 0, stream>>>(x, Wq, Wk, Wv, xb, wqkv);

  // 2) fused QKV projection: cols 0-2047 -> qkb, cols 2048-3071 -> vtb (transposed)
  gemm_bt<3><<<dim3(MTOT / 128, 3072 / 128, 1), 256, 0, stream>>>(
      xb, wqkv, bq, bk, bv, qkb, vtb, CC, CC, CC, 0, 1.f, 0, 0, 0);

  // 3) scores S[b] = Q[b] K[b]^T / 32  (fp32 out; overwrites dead xb/wqkv)
  gemm_bt<0><<<dim3(NN / 128, NN / 128, BB), 256, 0, stream>>>(
      qkb, qkb + 1024, nullptr, nullptr, nullptr, S, nullptr, CC, 2048, 2048, NN,
      1.f / 32.f, (long)NN * 2048, (long)NN * 2048, (long)NN * NN);

  // 4) exact top-k + softmax -> compact P f16 (over dead qkb)
  topk_softmax_kernel<<<MTOT, 256, 0, stream>>>(S, Pc);

  // 5) O[b] = P[b] Vt[b]^T  (fp32 out to d_out)
  gemm_bt<0><<<dim3(NN / 128, CC / 128, BB), 256, 0, stream>>>(
      Pc, vtb, nullptr, nullptr, nullptr, out, nullptr, NN, NN, MTOT, CC, 1.f,
      (long)NN * NN, (long)NN, (long)NN * CC);
}